// Round 1
// baseline (1149.824 us; speedup 1.0000x reference)
//
#include <hip/hip_runtime.h>
#include <hip/hip_bf16.h>

#define T_STEPS 512
#define B_SZ 64
#define H_SZ 96
#define I_SZ 2048

// ---------------- GEMM: xproj0 = x @ w_ih0^T + b_ih0 (unchanged) ----------------
#define BM 64
#define BN 96
#define BK 32

typedef const __attribute__((address_space(1))) void g_void;
typedef __attribute__((address_space(3))) void l_void;

__device__ __forceinline__ void stage_tile(const float* __restrict__ x,
                                           const float* __restrict__ w,
                                           float* xsf, float* wsf,
                                           int buf, int m0, int k0, int tid) {
#pragma unroll
    for (int it = 0; it < 2; ++it) {
        int L = tid + it * 256;              // 0..511
        int m = L >> 3;                      // 0..63
        int c = (L & 7) ^ ((L >> 5) & 7);    // swizzled k-chunk
        const float* g = &x[(size_t)(m0 + m) * I_SZ + k0 + c * 4];
        __builtin_amdgcn_global_load_lds((g_void*)g,
            (l_void*)(xsf + buf * (BM * BK) + L * 4), 16, 0, 0);
    }
#pragma unroll
    for (int it = 0; it < 3; ++it) {
        int L = tid + it * 256;              // 0..767
        int j = L >> 3;                      // 0..95
        int c = (L & 7) ^ ((L >> 5) & 7);
        const float* g = &w[(size_t)j * I_SZ + k0 + c * 4];
        __builtin_amdgcn_global_load_lds((g_void*)g,
            (l_void*)(wsf + buf * (BN * BK) + L * 4), 16, 0, 0);
    }
}

__global__ __launch_bounds__(256) void xproj_gemm(
    const float* __restrict__ x,    // [32768, 2048]
    const float* __restrict__ w,    // [96, 2048]
    const float* __restrict__ bias, // [96]
    float* __restrict__ out)        // [32768, 96]
{
    __shared__ __align__(16) float xsf[2 * BM * BK];
    __shared__ __align__(16) float wsf[2 * BN * BK];

    const int tid = threadIdx.x;
    const int m0 = blockIdx.x * BM;
    const int tm = tid & 15;
    const int tn = tid >> 4;

    float bb[6];
#pragma unroll
    for (int c = 0; c < 6; ++c) bb[c] = bias[tn * 6 + c];

    int aoff[4], boff[6], sb[6];
    const int sa = tm & 7;
#pragma unroll
    for (int r = 0; r < 4; ++r) aoff[r] = (tm * 4 + r) * 8;
#pragma unroll
    for (int c = 0; c < 6; ++c) {
        int j = tn * 6 + c;
        boff[c] = j * 8;
        sb[c] = (j >> 2) & 7;
    }

    float acc[4][6];
#pragma unroll
    for (int r = 0; r < 4; ++r)
#pragma unroll
        for (int c = 0; c < 6; ++c) acc[r][c] = 0.f;

    stage_tile(x, w, xsf, wsf, 0, m0, 0, tid);
    __syncthreads();

    for (int tile = 0; tile < I_SZ / BK; ++tile) {
        const int buf = tile & 1;
        if (tile < I_SZ / BK - 1)
            stage_tile(x, w, xsf, wsf, buf ^ 1, m0, (tile + 1) * BK, tid);

        const float4* xsb = (const float4*)(xsf + buf * (BM * BK));
        const float4* wsb = (const float4*)(wsf + buf * (BN * BK));
#pragma unroll
        for (int cc = 0; cc < 8; ++cc) {
            float av[4][4], bv[6][4];
#pragma unroll
            for (int r = 0; r < 4; ++r)
                *(float4*)av[r] = xsb[aoff[r] + (cc ^ sa)];
#pragma unroll
            for (int c = 0; c < 6; ++c)
                *(float4*)bv[c] = wsb[boff[c] + (cc ^ sb[c])];
#pragma unroll
            for (int kk = 0; kk < 4; ++kk)
#pragma unroll
                for (int r = 0; r < 4; ++r)
#pragma unroll
                    for (int c = 0; c < 6; ++c)
                        acc[r][c] = fmaf(av[r][kk], bv[c][kk], acc[r][c]);
        }
        __syncthreads();
    }

#pragma unroll
    for (int r = 0; r < 4; ++r) {
        float* op = &out[(size_t)(m0 + tm * 4 + r) * H_SZ + tn * 6];
        *(float2*)(op + 0) = make_float2(acc[r][0] + bb[0], acc[r][1] + bb[1]);
        *(float2*)(op + 2) = make_float2(acc[r][2] + bb[2], acc[r][3] + bb[3]);
        *(float2*)(op + 4) = make_float2(acc[r][4] + bb[4], acc[r][5] + bb[5]);
    }
}

// ---------------- Fused RNN v2: periodized wave-specialized pipeline ----------------
// 64 blocks x 512 threads (8 waves). Period PP=8 ticks, ONE barrier per period.
//   wave0: layer0 hh-recurrence (wave-local, barrier-free within a period)
//   wave1: layer1 hh-recurrence (lag 2 periods)
//   wave2: layer2 hh-recurrence (lag 4 periods)
//   waves 3,4: bulk ihdot1[t][j] = W_ih1 . h0[t]  (chunk m-1, one row/lane in regs)
//   waves 6,7: bulk ihdot2[t][j] = W_ih2 . h1[t]  (chunk m-3)
//   wave 5:   stages xproj chunk m+1 into LDS
// Serial wave decomposition: lane pair p=(l>>1) owns rows {3p,3p+1,3p+2},
// lane covers k-half kh=(l&1) (48 k). Combine = 1x shfl_xor(1). h written to a
// 32-slot LDS ring, re-read by the same wave (lockstep + lgkmcnt -> no barrier).
// Register union: R[0..35]=serial W, R[36..47]=serial h | R[0..23]=bulk row.

#define PP 8
#define RING 32
#define NCH (T_STEPS / PP)        // 64 chunks
#define NPER (NCH + 4)            // 68 periods (pipeline fill = 4)

__device__ __forceinline__ float fast_tanh(float x) {
    float cx = fminf(fmaxf(x, -15.f), 15.f);
    float e = __expf(2.f * cx);
    return 1.f - 2.f / (e + 1.f);
}

__device__ __forceinline__ void serial_chunk(
    float4 (&R)[48], float cb0, float cb1, float cb2,
    float* __restrict__ ringS, const float* __restrict__ ihsrc,
    int tb, int p, int kh)
{
    const int j0 = 3 * p;
    const int hbase = kh * 48;
#pragma unroll
    for (int i8 = 0; i8 < PP; ++i8) {
        const int sofs = ((tb + i8) & (RING - 1)) * H_SZ;
        float id0 = ihsrc[i8 * H_SZ + j0 + 0];
        float id1 = ihsrc[i8 * H_SZ + j0 + 1];
        float id2 = ihsrc[i8 * H_SZ + j0 + 2];
        float a0x = 0.f, a0y = 0.f, a0z = 0.f, a0w = 0.f;
        float a1x = 0.f, a1y = 0.f, a1z = 0.f, a1w = 0.f;
        float a2x = 0.f, a2y = 0.f, a2z = 0.f, a2w = 0.f;
#pragma unroll
        for (int c = 0; c < 12; ++c) {
            float4 h = R[36 + c];
            a0x = fmaf(R[c].x,      h.x, a0x); a0y = fmaf(R[c].y,      h.y, a0y);
            a0z = fmaf(R[c].z,      h.z, a0z); a0w = fmaf(R[c].w,      h.w, a0w);
            a1x = fmaf(R[12 + c].x, h.x, a1x); a1y = fmaf(R[12 + c].y, h.y, a1y);
            a1z = fmaf(R[12 + c].z, h.z, a1z); a1w = fmaf(R[12 + c].w, h.w, a1w);
            a2x = fmaf(R[24 + c].x, h.x, a2x); a2y = fmaf(R[24 + c].y, h.y, a2y);
            a2z = fmaf(R[24 + c].z, h.z, a2z); a2w = fmaf(R[24 + c].w, h.w, a2w);
        }
        float a0 = (a0x + a0y) + (a0z + a0w);
        float a1 = (a1x + a1y) + (a1z + a1w);
        float a2 = (a2x + a2y) + (a2z + a2w);
        a0 += __shfl_xor(a0, 1, 64);
        a1 += __shfl_xor(a1, 1, 64);
        a2 += __shfl_xor(a2, 1, 64);
        float h0v = fast_tanh(a0 + id0 + cb0);
        float h1v = fast_tanh(a1 + id1 + cb1);
        float h2v = fast_tanh(a2 + id2 + cb2);
        if (kh == 0) {
            ringS[sofs + j0 + 0] = h0v;
            ringS[sofs + j0 + 1] = h1v;
        } else {
            ringS[sofs + j0 + 2] = h2v;
        }
        // re-broadcast new h into regs for next tick (same wave: lockstep +
        // compiler-inserted lgkmcnt orders write->read; no barrier needed)
#pragma unroll
        for (int c = 0; c < 12; ++c)
            R[36 + c] = *(const float4*)&ringS[sofs + hbase + c * 4];
    }
}

__device__ __forceinline__ void bulk_chunk(
    float4 (&R)[48], const float* __restrict__ ringSrc,
    float* __restrict__ dst, int tb, int row, bool act)
{
#pragma unroll
    for (int i8 = 0; i8 < PP; ++i8) {
        const int sofs = ((tb + i8) & (RING - 1)) * H_SZ;
        float ax = 0.f, ay = 0.f, az = 0.f, aw = 0.f;
#pragma unroll
        for (int c = 0; c < 24; ++c) {
            float4 h = *(const float4*)&ringSrc[sofs + c * 4];  // broadcast read
            ax = fmaf(R[c].x, h.x, ax); ay = fmaf(R[c].y, h.y, ay);
            az = fmaf(R[c].z, h.z, az); aw = fmaf(R[c].w, h.w, aw);
        }
        if (act) dst[i8 * H_SZ + row] = (ax + ay) + (az + aw);
    }
}

__global__ __launch_bounds__(512, 2) void rnn3_fused(
    const float* __restrict__ xproj0, // [B*T, 96], includes b_ih0
    const float* __restrict__ w_hh0, const float* __restrict__ b_hh0,
    const float* __restrict__ w_ih1, const float* __restrict__ b_ih1,
    const float* __restrict__ w_hh1, const float* __restrict__ b_hh1,
    const float* __restrict__ w_ih2, const float* __restrict__ b_ih2,
    const float* __restrict__ w_hh2, const float* __restrict__ b_hh2,
    const float* __restrict__ fc_w, const float* __restrict__ fc_b,
    float* __restrict__ out)          // [B]
{
    __shared__ __align__(16) float ring0[RING * H_SZ];   // 12 KB each
    __shared__ __align__(16) float ring1[RING * H_SZ];
    __shared__ __align__(16) float ring2[RING * H_SZ];
    __shared__ __align__(16) float ihd1[2][PP * H_SZ];   // 6 KB
    __shared__ __align__(16) float ihd2[2][PP * H_SZ];
    __shared__ __align__(16) float xpb[2][PP * H_SZ];
    __shared__ float red[H_SZ];

    const int t = threadIdx.x;
    const int b = blockIdx.x;
    const int wv = t >> 6;
    const int l = t & 63;
    const int p = l >> 1, kh = l & 1;

    // zero rings (h[-1] = 0 for bulk readers)
    for (int k = t; k < RING * H_SZ; k += 512) {
        ring0[k] = 0.f; ring1[k] = 0.f; ring2[k] = 0.f;
    }

    const float* xp_base = xproj0 + (size_t)b * T_STEPS * H_SZ;

    float4 R[48];
    float cb0 = 0.f, cb1 = 0.f, cb2 = 0.f;
    int rowid = 0;
    bool rowact = false;

    if (wv < 3) {
        const float* wm = (wv == 0) ? w_hh0 : (wv == 1 ? w_hh1 : w_hh2);
        const int j0 = 3 * p;
#pragma unroll
        for (int r = 0; r < 3; ++r)
#pragma unroll
            for (int c = 0; c < 12; ++c)
                R[r * 12 + c] = *(const float4*)&wm[(j0 + r) * H_SZ + kh * 48 + c * 4];
#pragma unroll
        for (int c = 0; c < 12; ++c) R[36 + c] = make_float4(0.f, 0.f, 0.f, 0.f);
        if (wv == 0) {
            cb0 = b_hh0[j0]; cb1 = b_hh0[j0 + 1]; cb2 = b_hh0[j0 + 2];
        } else if (wv == 1) {
            cb0 = b_ih1[j0]     + b_hh1[j0];
            cb1 = b_ih1[j0 + 1] + b_hh1[j0 + 1];
            cb2 = b_ih1[j0 + 2] + b_hh1[j0 + 2];
        } else {
            cb0 = b_ih2[j0]     + b_hh2[j0];
            cb1 = b_ih2[j0 + 1] + b_hh2[j0 + 1];
            cb2 = b_ih2[j0 + 2] + b_hh2[j0 + 2];
        }
        __builtin_amdgcn_s_setprio(1);   // serial waves are the critical path
    } else if (wv == 3 || wv == 4) {
        int rr = (wv - 3) * 64 + l;
        rowact = rr < H_SZ; rowid = rowact ? rr : (H_SZ - 1);
#pragma unroll
        for (int c = 0; c < 24; ++c)
            R[c] = *(const float4*)&w_ih1[rowid * H_SZ + c * 4];
    } else if (wv >= 6) {
        int rr = (wv - 6) * 64 + l;
        rowact = rr < H_SZ; rowid = rowact ? rr : (H_SZ - 1);
#pragma unroll
        for (int c = 0; c < 24; ++c)
            R[c] = *(const float4*)&w_ih2[rowid * H_SZ + c * 4];
    } else { // wv == 5: prologue-stage xproj chunk 0
#pragma unroll
        for (int q = 0; q < 3; ++q) {
            int idx = (l + 64 * q) * 4;
            *(float4*)&xpb[0][idx] = *(const float4*)&xp_base[idx];
        }
    }
    __syncthreads();

    for (int m = 0; m < NPER; ++m) {
        if (wv == 0) {
            if (m < NCH)
                serial_chunk(R, cb0, cb1, cb2, ring0, &xpb[m & 1][0], m * PP, p, kh);
        } else if (wv == 1) {
            int cc = m - 2;
            if (cc >= 0 && cc < NCH)
                serial_chunk(R, cb0, cb1, cb2, ring1, &ihd1[cc & 1][0], cc * PP, p, kh);
        } else if (wv == 2) {
            int cc = m - 4;
            if (cc >= 0 && cc < NCH)
                serial_chunk(R, cb0, cb1, cb2, ring2, &ihd2[cc & 1][0], cc * PP, p, kh);
        } else if (wv == 3 || wv == 4) {
            int cc = m - 1;
            if (cc >= 0 && cc < NCH)
                bulk_chunk(R, ring0, &ihd1[cc & 1][0], cc * PP, rowid, rowact);
        } else if (wv == 5) {
            int cs = m + 1;
            if (cs < NCH) {
                const float* src = xp_base + (size_t)cs * PP * H_SZ;
                float* dstx = &xpb[cs & 1][0];
#pragma unroll
                for (int q = 0; q < 3; ++q) {
                    int idx = (l + 64 * q) * 4;
                    *(float4*)&dstx[idx] = *(const float4*)&src[idx];
                }
            }
        } else {
            int cc = m - 3;
            if (cc >= 0 && cc < NCH)
                bulk_chunk(R, ring1, &ihd2[cc & 1][0], cc * PP, rowid, rowact);
        }
        __syncthreads();
    }

    // h2[T-1] lives in ring2 slot (T-1)&31 = 31
    if (t < H_SZ) red[t] = ring2[((T_STEPS - 1) & (RING - 1)) * H_SZ + t] * fc_w[t];
    __syncthreads();
    if (t == 0) {
        float sm = 0.f;
#pragma unroll
        for (int k = 0; k < H_SZ; ++k) sm += red[k];
        out[b] = sm + fc_b[0];
    }
}

// ---------------- launcher ----------------
extern "C" void kernel_launch(void* const* d_in, const int* in_sizes, int n_in,
                              void* d_out, int out_size, void* d_ws, size_t ws_size,
                              hipStream_t stream) {
    const float* x     = (const float*)d_in[0];
    const float* w_ih0 = (const float*)d_in[1];
    const float* w_hh0 = (const float*)d_in[2];
    const float* b_ih0 = (const float*)d_in[3];
    const float* b_hh0 = (const float*)d_in[4];
    const float* w_ih1 = (const float*)d_in[5];
    const float* w_hh1 = (const float*)d_in[6];
    const float* b_ih1 = (const float*)d_in[7];
    const float* b_hh1 = (const float*)d_in[8];
    const float* w_ih2 = (const float*)d_in[9];
    const float* w_hh2 = (const float*)d_in[10];
    const float* b_ih2 = (const float*)d_in[11];
    const float* b_hh2 = (const float*)d_in[12];
    const float* fc_w  = (const float*)d_in[13];
    const float* fc_b  = (const float*)d_in[14];

    float* xproj = (float*)d_ws;  // 32768 * 96 floats = 12.6 MB

    const int M = B_SZ * T_STEPS; // 32768
    xproj_gemm<<<M / BM, 256, 0, stream>>>(x, w_ih0, b_ih0, xproj);
    rnn3_fused<<<B_SZ, 512, 0, stream>>>(xproj,
                                         w_hh0, b_hh0,
                                         w_ih1, b_ih1, w_hh1, b_hh1,
                                         w_ih2, b_ih2, w_hh2, b_hh2,
                                         fc_w, fc_b, (float*)d_out);
}

// Round 2
// 858.219 us; speedup vs baseline: 1.3398x; 1.3398x over previous
//
#include <hip/hip_runtime.h>
#include <hip/hip_bf16.h>

#define T_STEPS 512
#define B_SZ 64
#define H_SZ 96
#define I_SZ 2048

// ---------------- GEMM: xproj0 = x @ w_ih0^T + b_ih0 (unchanged) ----------------
#define BM 64
#define BN 96
#define BK 32

typedef const __attribute__((address_space(1))) void g_void;
typedef __attribute__((address_space(3))) void l_void;

__device__ __forceinline__ void stage_tile(const float* __restrict__ x,
                                           const float* __restrict__ w,
                                           float* xsf, float* wsf,
                                           int buf, int m0, int k0, int tid) {
#pragma unroll
    for (int it = 0; it < 2; ++it) {
        int L = tid + it * 256;              // 0..511
        int m = L >> 3;                      // 0..63
        int c = (L & 7) ^ ((L >> 5) & 7);    // swizzled k-chunk
        const float* g = &x[(size_t)(m0 + m) * I_SZ + k0 + c * 4];
        __builtin_amdgcn_global_load_lds((g_void*)g,
            (l_void*)(xsf + buf * (BM * BK) + L * 4), 16, 0, 0);
    }
#pragma unroll
    for (int it = 0; it < 3; ++it) {
        int L = tid + it * 256;              // 0..767
        int j = L >> 3;                      // 0..95
        int c = (L & 7) ^ ((L >> 5) & 7);
        const float* g = &w[(size_t)j * I_SZ + k0 + c * 4];
        __builtin_amdgcn_global_load_lds((g_void*)g,
            (l_void*)(wsf + buf * (BN * BK) + L * 4), 16, 0, 0);
    }
}

__global__ __launch_bounds__(256) void xproj_gemm(
    const float* __restrict__ x,    // [32768, 2048]
    const float* __restrict__ w,    // [96, 2048]
    const float* __restrict__ bias, // [96]
    float* __restrict__ out)        // [32768, 96]
{
    __shared__ __align__(16) float xsf[2 * BM * BK];
    __shared__ __align__(16) float wsf[2 * BN * BK];

    const int tid = threadIdx.x;
    const int m0 = blockIdx.x * BM;
    const int tm = tid & 15;
    const int tn = tid >> 4;

    float bb[6];
#pragma unroll
    for (int c = 0; c < 6; ++c) bb[c] = bias[tn * 6 + c];

    int aoff[4], boff[6], sb[6];
    const int sa = tm & 7;
#pragma unroll
    for (int r = 0; r < 4; ++r) aoff[r] = (tm * 4 + r) * 8;
#pragma unroll
    for (int c = 0; c < 6; ++c) {
        int j = tn * 6 + c;
        boff[c] = j * 8;
        sb[c] = (j >> 2) & 7;
    }

    float acc[4][6];
#pragma unroll
    for (int r = 0; r < 4; ++r)
#pragma unroll
        for (int c = 0; c < 6; ++c) acc[r][c] = 0.f;

    stage_tile(x, w, xsf, wsf, 0, m0, 0, tid);
    __syncthreads();

    for (int tile = 0; tile < I_SZ / BK; ++tile) {
        const int buf = tile & 1;
        if (tile < I_SZ / BK - 1)
            stage_tile(x, w, xsf, wsf, buf ^ 1, m0, (tile + 1) * BK, tid);

        const float4* xsb = (const float4*)(xsf + buf * (BM * BK));
        const float4* wsb = (const float4*)(wsf + buf * (BN * BK));
#pragma unroll
        for (int cc = 0; cc < 8; ++cc) {
            float av[4][4], bv[6][4];
#pragma unroll
            for (int r = 0; r < 4; ++r)
                *(float4*)av[r] = xsb[aoff[r] + (cc ^ sa)];
#pragma unroll
            for (int c = 0; c < 6; ++c)
                *(float4*)bv[c] = wsb[boff[c] + (cc ^ sb[c])];
#pragma unroll
            for (int kk = 0; kk < 4; ++kk)
#pragma unroll
                for (int r = 0; r < 4; ++r)
#pragma unroll
                    for (int c = 0; c < 6; ++c)
                        acc[r][c] = fmaf(av[r][kk], bv[c][kk], acc[r][c]);
        }
        __syncthreads();
    }

#pragma unroll
    for (int r = 0; r < 4; ++r) {
        float* op = &out[(size_t)(m0 + tm * 4 + r) * H_SZ + tn * 6];
        *(float2*)(op + 0) = make_float2(acc[r][0] + bb[0], acc[r][1] + bb[1]);
        *(float2*)(op + 2) = make_float2(acc[r][2] + bb[2], acc[r][3] + bb[3]);
        *(float2*)(op + 4) = make_float2(acc[r][4] + bb[4], acc[r][5] + bb[5]);
    }
}

// ---------------- Fused RNN v3: wave-specialized pipeline, spill-free ----------------
// 64 blocks x 512 threads (8 waves). Period PP=8 ticks, ONE barrier per period.
// Each wave ROLE runs its OWN loop (separate register scopes -> no cross-branch
// register union -> no spill). Every role executes exactly NPER barriers.
//   wave0: layer0 hh-recurrence (chunk m)
//   wave1: layer1 hh-recurrence (chunk m-2)
//   wave2: layer2 hh-recurrence (chunk m-4)
//   waves 3,4: ihdot1[t][j] = W_ih1 . h0[t]  (chunk m-1)
//   waves 6,7: ihdot2[t][j] = W_ih2 . h1[t]  (chunk m-3)
//   wave 5:   stages xproj chunk m+1
// Serial decomposition: lane pair p=(l>>1) owns rows {3p,3p+1,3p+2}; lane covers
// k-half kh=(l&1). h[t-1] read from LDS ring at tick start (transient regs only).

#define PP 8
#define RING 32
#define NCH (T_STEPS / PP)        // 64 chunks
#define NPER (NCH + 4)            // 68 periods

__device__ __forceinline__ float fast_tanh(float x) {
    float cx = fminf(fmaxf(x, -15.f), 15.f);
    float e = __expf(2.f * cx);
    return 1.f - 2.f / (e + 1.f);
}

__device__ __forceinline__ void serial_chunk(
    const float4 (&W)[36], float cb0, float cb1, float cb2,
    float* ringS, const float* ihsrc, int tb, int p, int kh)
{
    const int j0 = 3 * p;
    const int hbase = kh * 48;
#pragma unroll
    for (int i8 = 0; i8 < PP; ++i8) {
        const int tt = tb + i8;
        const float* hp = &ringS[((tt - 1) & (RING - 1)) * H_SZ + hbase];
        const float* ih = &ihsrc[i8 * H_SZ + j0];
        float id0 = ih[0], id1 = ih[1], id2 = ih[2];
        float a0x = 0.f, a0y = 0.f, a0z = 0.f, a0w = 0.f;
        float a1x = 0.f, a1y = 0.f, a1z = 0.f, a1w = 0.f;
        float a2x = 0.f, a2y = 0.f, a2z = 0.f, a2w = 0.f;
#pragma unroll
        for (int c = 0; c < 12; ++c) {
            float4 h = *(const float4*)(hp + c * 4);
            a0x = fmaf(W[c].x,      h.x, a0x); a0y = fmaf(W[c].y,      h.y, a0y);
            a0z = fmaf(W[c].z,      h.z, a0z); a0w = fmaf(W[c].w,      h.w, a0w);
            a1x = fmaf(W[12 + c].x, h.x, a1x); a1y = fmaf(W[12 + c].y, h.y, a1y);
            a1z = fmaf(W[12 + c].z, h.z, a1z); a1w = fmaf(W[12 + c].w, h.w, a1w);
            a2x = fmaf(W[24 + c].x, h.x, a2x); a2y = fmaf(W[24 + c].y, h.y, a2y);
            a2z = fmaf(W[24 + c].z, h.z, a2z); a2w = fmaf(W[24 + c].w, h.w, a2w);
        }
        float a0 = (a0x + a0y) + (a0z + a0w);
        float a1 = (a1x + a1y) + (a1z + a1w);
        float a2 = (a2x + a2y) + (a2z + a2w);
        a0 += __shfl_xor(a0, 1, 64);
        a1 += __shfl_xor(a1, 1, 64);
        a2 += __shfl_xor(a2, 1, 64);
        float h0v = fast_tanh(a0 + id0 + cb0);
        float h1v = fast_tanh(a1 + id1 + cb1);
        float h2v = fast_tanh(a2 + id2 + cb2);
        const int so = (tt & (RING - 1)) * H_SZ;
        if (kh == 0) {
            ringS[so + j0 + 0] = h0v;
            ringS[so + j0 + 1] = h1v;
        } else {
            ringS[so + j0 + 2] = h2v;
        }
    }
}

__device__ __forceinline__ void bulk_chunk(
    const float4 (&W)[24], const float* ringSrc,
    float* dst, int tb, int row, bool act)
{
#pragma unroll
    for (int i8 = 0; i8 < PP; ++i8) {
        const float* hp = &ringSrc[((tb + i8) & (RING - 1)) * H_SZ];
        float ax = 0.f, ay = 0.f, az = 0.f, aw = 0.f;
#pragma unroll
        for (int c = 0; c < 24; ++c) {
            float4 h = *(const float4*)(hp + c * 4);   // broadcast read
            ax = fmaf(W[c].x, h.x, ax); ay = fmaf(W[c].y, h.y, ay);
            az = fmaf(W[c].z, h.z, az); aw = fmaf(W[c].w, h.w, aw);
        }
        if (act) dst[i8 * H_SZ + row] = (ax + ay) + (az + aw);
    }
}

__global__ __launch_bounds__(512, 2) void rnn3_fused(
    const float* __restrict__ xproj0, // [B*T, 96], includes b_ih0
    const float* __restrict__ w_hh0, const float* __restrict__ b_hh0,
    const float* __restrict__ w_ih1, const float* __restrict__ b_ih1,
    const float* __restrict__ w_hh1, const float* __restrict__ b_hh1,
    const float* __restrict__ w_ih2, const float* __restrict__ b_ih2,
    const float* __restrict__ w_hh2, const float* __restrict__ b_hh2,
    const float* __restrict__ fc_w, const float* __restrict__ fc_b,
    float* __restrict__ out)          // [B]
{
    __shared__ __align__(16) float ring0[RING * H_SZ];   // 12 KB each
    __shared__ __align__(16) float ring1[RING * H_SZ];
    __shared__ __align__(16) float ring2[RING * H_SZ];
    __shared__ __align__(16) float ihd1[2][PP * H_SZ];   // 3 KB each
    __shared__ __align__(16) float ihd2[2][PP * H_SZ];
    __shared__ __align__(16) float xpb[2][PP * H_SZ];
    __shared__ float red[H_SZ];

    const int t = threadIdx.x;
    const int b = blockIdx.x;
    const int wv = t >> 6;
    const int l = t & 63;

    // zero rings (h[-1] = 0 and pipeline-fill safety)
    for (int k = t; k < RING * H_SZ; k += 512) {
        ring0[k] = 0.f; ring1[k] = 0.f; ring2[k] = 0.f;
    }

    const float* xp_base = xproj0 + (size_t)b * T_STEPS * H_SZ;

    // prologue: wave 5 stages xproj chunk 0
    if (wv == 5) {
#pragma unroll
        for (int q = 0; q < 3; ++q) {
            int idx = (l + 64 * q) * 4;
            *(float4*)&xpb[0][idx] = *(const float4*)&xp_base[idx];
        }
    }
    __syncthreads();

    if (wv < 3) {
        // ---- serial recurrence role (own scope: W lives only here) ----
        const int p = l >> 1, kh = l & 1, j0 = 3 * p;
        const float* wm = (wv == 0) ? w_hh0 : (wv == 1 ? w_hh1 : w_hh2);
        float4 W[36];
#pragma unroll
        for (int r = 0; r < 3; ++r)
#pragma unroll
            for (int c = 0; c < 12; ++c)
                W[r * 12 + c] = *(const float4*)&wm[(j0 + r) * H_SZ + kh * 48 + c * 4];
        float cb0, cb1, cb2;
        if (wv == 0) {
            cb0 = b_hh0[j0]; cb1 = b_hh0[j0 + 1]; cb2 = b_hh0[j0 + 2];
        } else if (wv == 1) {
            cb0 = b_ih1[j0]     + b_hh1[j0];
            cb1 = b_ih1[j0 + 1] + b_hh1[j0 + 1];
            cb2 = b_ih1[j0 + 2] + b_hh1[j0 + 2];
        } else {
            cb0 = b_ih2[j0]     + b_hh2[j0];
            cb1 = b_ih2[j0 + 1] + b_hh2[j0 + 1];
            cb2 = b_ih2[j0 + 2] + b_hh2[j0 + 2];
        }
        float* ringS = (wv == 0) ? ring0 : (wv == 1 ? ring1 : ring2);
        __builtin_amdgcn_s_setprio(1);   // serial waves are the critical path
        for (int m = 0; m < NPER; ++m) {
            const int cc = m - 2 * wv;   // wv0: m, wv1: m-2, wv2: m-4
            if (cc >= 0 && cc < NCH) {
                const float* ihsrc = (wv == 0) ? &xpb[m & 1][0]
                                   : (wv == 1) ? &ihd1[cc & 1][0]
                                               : &ihd2[cc & 1][0];
                serial_chunk(W, cb0, cb1, cb2, ringS, ihsrc, cc * PP, p, kh);
            }
            __syncthreads();
        }
        __builtin_amdgcn_s_setprio(0);
    } else if (wv == 3 || wv == 4) {
        // ---- bulk ih1 role ----
        const int rr = (wv - 3) * 64 + l;
        const bool rowact = rr < H_SZ;
        const int rowid = rowact ? rr : (H_SZ - 1);
        float4 W[24];
#pragma unroll
        for (int c = 0; c < 24; ++c)
            W[c] = *(const float4*)&w_ih1[rowid * H_SZ + c * 4];
        for (int m = 0; m < NPER; ++m) {
            const int cc = m - 1;
            if (cc >= 0 && cc < NCH)
                bulk_chunk(W, ring0, &ihd1[cc & 1][0], cc * PP, rowid, rowact);
            __syncthreads();
        }
    } else if (wv == 5) {
        // ---- xproj staging role ----
        for (int m = 0; m < NPER; ++m) {
            const int cs = m + 1;
            if (cs < NCH) {
                const float* src = xp_base + (size_t)cs * PP * H_SZ;
                float* dstx = &xpb[cs & 1][0];
#pragma unroll
                for (int q = 0; q < 3; ++q) {
                    int idx = (l + 64 * q) * 4;
                    *(float4*)&dstx[idx] = *(const float4*)&src[idx];
                }
            }
            __syncthreads();
        }
    } else {
        // ---- bulk ih2 role (wv 6,7) ----
        const int rr = (wv - 6) * 64 + l;
        const bool rowact = rr < H_SZ;
        const int rowid = rowact ? rr : (H_SZ - 1);
        float4 W[24];
#pragma unroll
        for (int c = 0; c < 24; ++c)
            W[c] = *(const float4*)&w_ih2[rowid * H_SZ + c * 4];
        for (int m = 0; m < NPER; ++m) {
            const int cc = m - 3;
            if (cc >= 0 && cc < NCH)
                bulk_chunk(W, ring1, &ihd2[cc & 1][0], cc * PP, rowid, rowact);
            __syncthreads();
        }
    }
    __syncthreads();

    // h2[T-1] lives in ring2 slot (T-1)&31 = 31
    if (t < H_SZ) red[t] = ring2[((T_STEPS - 1) & (RING - 1)) * H_SZ + t] * fc_w[t];
    __syncthreads();
    if (t == 0) {
        float sm = 0.f;
#pragma unroll
        for (int k = 0; k < H_SZ; ++k) sm += red[k];
        out[b] = sm + fc_b[0];
    }
}

// ---------------- launcher ----------------
extern "C" void kernel_launch(void* const* d_in, const int* in_sizes, int n_in,
                              void* d_out, int out_size, void* d_ws, size_t ws_size,
                              hipStream_t stream) {
    const float* x     = (const float*)d_in[0];
    const float* w_ih0 = (const float*)d_in[1];
    const float* w_hh0 = (const float*)d_in[2];
    const float* b_ih0 = (const float*)d_in[3];
    const float* b_hh0 = (const float*)d_in[4];
    const float* w_ih1 = (const float*)d_in[5];
    const float* w_hh1 = (const float*)d_in[6];
    const float* b_ih1 = (const float*)d_in[7];
    const float* b_hh1 = (const float*)d_in[8];
    const float* w_ih2 = (const float*)d_in[9];
    const float* w_hh2 = (const float*)d_in[10];
    const float* b_ih2 = (const float*)d_in[11];
    const float* b_hh2 = (const float*)d_in[12];
    const float* fc_w  = (const float*)d_in[13];
    const float* fc_b  = (const float*)d_in[14];

    float* xproj = (float*)d_ws;  // 32768 * 96 floats = 12.6 MB

    const int M = B_SZ * T_STEPS; // 32768
    xproj_gemm<<<M / BM, 256, 0, stream>>>(x, w_ih0, b_ih0, xproj);
    rnn3_fused<<<B_SZ, 512, 0, stream>>>(xproj,
                                         w_hh0, b_hh0,
                                         w_ih1, b_ih1, w_hh1, b_hh1,
                                         w_ih2, b_ih2, w_hh2, b_hh2,
                                         fc_w, fc_b, (float*)d_out);
}

// Round 4
// 839.972 us; speedup vs baseline: 1.3689x; 1.0217x over previous
//
#include <hip/hip_runtime.h>
#include <hip/hip_bf16.h>

#define T_STEPS 512
#define B_SZ 64
#define H_SZ 96
#define I_SZ 2048

// ---------------- GEMM: xproj0 = x @ w_ih0^T + b_ih0 (unchanged) ----------------
#define BM 64
#define BN 96
#define BK 32

typedef const __attribute__((address_space(1))) void g_void;
typedef __attribute__((address_space(3))) void l_void;

__device__ __forceinline__ void stage_tile(const float* __restrict__ x,
                                           const float* __restrict__ w,
                                           float* xsf, float* wsf,
                                           int buf, int m0, int k0, int tid) {
#pragma unroll
    for (int it = 0; it < 2; ++it) {
        int L = tid + it * 256;              // 0..511
        int m = L >> 3;                      // 0..63
        int c = (L & 7) ^ ((L >> 5) & 7);    // swizzled k-chunk
        const float* g = &x[(size_t)(m0 + m) * I_SZ + k0 + c * 4];
        __builtin_amdgcn_global_load_lds((g_void*)g,
            (l_void*)(xsf + buf * (BM * BK) + L * 4), 16, 0, 0);
    }
#pragma unroll
    for (int it = 0; it < 3; ++it) {
        int L = tid + it * 256;              // 0..767
        int j = L >> 3;                      // 0..95
        int c = (L & 7) ^ ((L >> 5) & 7);
        const float* g = &w[(size_t)j * I_SZ + k0 + c * 4];
        __builtin_amdgcn_global_load_lds((g_void*)g,
            (l_void*)(wsf + buf * (BN * BK) + L * 4), 16, 0, 0);
    }
}

__global__ __launch_bounds__(256) void xproj_gemm(
    const float* __restrict__ x,    // [32768, 2048]
    const float* __restrict__ w,    // [96, 2048]
    const float* __restrict__ bias, // [96]
    float* __restrict__ out)        // [32768, 96]
{
    __shared__ __align__(16) float xsf[2 * BM * BK];
    __shared__ __align__(16) float wsf[2 * BN * BK];

    const int tid = threadIdx.x;
    const int m0 = blockIdx.x * BM;
    const int tm = tid & 15;
    const int tn = tid >> 4;

    float bb[6];
#pragma unroll
    for (int c = 0; c < 6; ++c) bb[c] = bias[tn * 6 + c];

    int aoff[4], boff[6], sb[6];
    const int sa = tm & 7;
#pragma unroll
    for (int r = 0; r < 4; ++r) aoff[r] = (tm * 4 + r) * 8;
#pragma unroll
    for (int c = 0; c < 6; ++c) {
        int j = tn * 6 + c;
        boff[c] = j * 8;
        sb[c] = (j >> 2) & 7;
    }

    float acc[4][6];
#pragma unroll
    for (int r = 0; r < 4; ++r)
#pragma unroll
        for (int c = 0; c < 6; ++c) acc[r][c] = 0.f;

    stage_tile(x, w, xsf, wsf, 0, m0, 0, tid);
    __syncthreads();

    for (int tile = 0; tile < I_SZ / BK; ++tile) {
        const int buf = tile & 1;
        if (tile < I_SZ / BK - 1)
            stage_tile(x, w, xsf, wsf, buf ^ 1, m0, (tile + 1) * BK, tid);

        const float4* xsb = (const float4*)(xsf + buf * (BM * BK));
        const float4* wsb = (const float4*)(wsf + buf * (BN * BK));
#pragma unroll
        for (int cc = 0; cc < 8; ++cc) {
            float av[4][4], bv[6][4];
#pragma unroll
            for (int r = 0; r < 4; ++r)
                *(float4*)av[r] = xsb[aoff[r] + (cc ^ sa)];
#pragma unroll
            for (int c = 0; c < 6; ++c)
                *(float4*)bv[c] = wsb[boff[c] + (cc ^ sb[c])];
#pragma unroll
            for (int kk = 0; kk < 4; ++kk)
#pragma unroll
                for (int r = 0; r < 4; ++r)
#pragma unroll
                    for (int c = 0; c < 6; ++c)
                        acc[r][c] = fmaf(av[r][kk], bv[c][kk], acc[r][c]);
        }
        __syncthreads();
    }

#pragma unroll
    for (int r = 0; r < 4; ++r) {
        float* op = &out[(size_t)(m0 + tm * 4 + r) * H_SZ + tn * 6];
        *(float2*)(op + 0) = make_float2(acc[r][0] + bb[0], acc[r][1] + bb[1]);
        *(float2*)(op + 2) = make_float2(acc[r][2] + bb[2], acc[r][3] + bb[3]);
        *(float2*)(op + 4) = make_float2(acc[r][4] + bb[4], acc[r][5] + bb[5]);
    }
}

// ---------------- Fused RNN v4b: DS-pipe-lean wave specialization ----------------
// 64 blocks x 384 threads (6 waves). Period PP=8 ticks, ONE barrier per period.
// The LDS instruction pipe is the shared bottleneck (v3: ~160 DS instr/tick ~
// 1571 cyc/tick measured). v4b cuts DS traffic to ~100 instr/tick by replacing
// the 4 broadcast-read bulk waves with 2 lean ih-waves using the same pair/kh
// split as the serial waves (12 b128 reads/tick each).
//   w0: layer0 hh recurrence (chunk m)       reads ring0(t-1) + xpb
//   w3: ih1[t] = W_ih1 . h0[t] (chunk m-1)   reads ring0(t)   -> ihd1
//   w1: layer1 hh recurrence (chunk m-2)     reads ring1(t-1) + ihd1
//   w4: ih2[t] = W_ih2 . h1[t] (chunk m-3)   reads ring1(t)   -> ihd2
//   w2: layer2 hh recurrence (chunk m-4)     reads ring2(t-1) + ihd2
//   w5: stages xproj chunk m+1 (register-staged float4, v3-proven pattern)
// All reader/writer ring-slot distances are 8 mod 32 -> no aliasing; all
// double-buffer parities disjoint; every role executes exactly NPER+1 barriers.

#define PP 8
#define RING 32
#define NCH (T_STEPS / PP)        // 64 chunks
#define NPER (NCH + 4)            // 68 periods (pipeline depth 4)

__device__ __forceinline__ float fast_tanh(float x) {
    float cx = fminf(fmaxf(x, -15.f), 15.f);
    float e = __expf(2.f * cx);
    return 1.f - 2.f / (e + 1.f);
}

// serial hh recurrence: lane pair p owns rows {3p,3p+1,3p+2}; lane covers
// k-half kh (48 floats = 12 b128 broadcast reads). One shfl set combines.
__device__ __forceinline__ void serial_chunk(
    const float4 (&W)[36], float cb0, float cb1, float cb2,
    float* ringS, const float* ihsrc, int tb, int p, int kh)
{
    const int j0 = 3 * p;
    const int hbase = kh * 48;
#pragma unroll
    for (int i8 = 0; i8 < PP; ++i8) {
        const int tt = tb + i8;
        const float* hp = &ringS[((tt - 1) & (RING - 1)) * H_SZ + hbase];
        const float* ih = &ihsrc[i8 * H_SZ + j0];
        float id0 = ih[0], id1 = ih[1], id2 = ih[2];
        float a0x = 0.f, a0y = 0.f, a0z = 0.f, a0w = 0.f;
        float a1x = 0.f, a1y = 0.f, a1z = 0.f, a1w = 0.f;
        float a2x = 0.f, a2y = 0.f, a2z = 0.f, a2w = 0.f;
#pragma unroll
        for (int c = 0; c < 12; ++c) {
            float4 h = *(const float4*)(hp + c * 4);
            a0x = fmaf(W[c].x,      h.x, a0x); a0y = fmaf(W[c].y,      h.y, a0y);
            a0z = fmaf(W[c].z,      h.z, a0z); a0w = fmaf(W[c].w,      h.w, a0w);
            a1x = fmaf(W[12 + c].x, h.x, a1x); a1y = fmaf(W[12 + c].y, h.y, a1y);
            a1z = fmaf(W[12 + c].z, h.z, a1z); a1w = fmaf(W[12 + c].w, h.w, a1w);
            a2x = fmaf(W[24 + c].x, h.x, a2x); a2y = fmaf(W[24 + c].y, h.y, a2y);
            a2z = fmaf(W[24 + c].z, h.z, a2z); a2w = fmaf(W[24 + c].w, h.w, a2w);
        }
        float a0 = (a0x + a0y) + (a0z + a0w);
        float a1 = (a1x + a1y) + (a1z + a1w);
        float a2 = (a2x + a2y) + (a2z + a2w);
        a0 += __shfl_xor(a0, 1, 64);
        a1 += __shfl_xor(a1, 1, 64);
        a2 += __shfl_xor(a2, 1, 64);
        float h0v = fast_tanh(a0 + id0 + cb0);
        float h1v = fast_tanh(a1 + id1 + cb1);
        float h2v = fast_tanh(a2 + id2 + cb2);
        const int so = (tt & (RING - 1)) * H_SZ;
        if (kh == 0) {
            ringS[so + j0 + 0] = h0v;
            ringS[so + j0 + 1] = h1v;
        } else {
            ringS[so + j0 + 2] = h2v;
        }
    }
}

// ih matvec: same decomposition, no recurrence (reads slot tt, pure dot)
__device__ __forceinline__ void ih_chunk(
    const float4 (&W)[36], const float* ringSrc,
    float* dst, int tb, int p, int kh)
{
    const int j0 = 3 * p;
    const int hbase = kh * 48;
#pragma unroll
    for (int i8 = 0; i8 < PP; ++i8) {
        const int tt = tb + i8;
        const float* hp = &ringSrc[(tt & (RING - 1)) * H_SZ + hbase];
        float a0x = 0.f, a0y = 0.f, a0z = 0.f, a0w = 0.f;
        float a1x = 0.f, a1y = 0.f, a1z = 0.f, a1w = 0.f;
        float a2x = 0.f, a2y = 0.f, a2z = 0.f, a2w = 0.f;
#pragma unroll
        for (int c = 0; c < 12; ++c) {
            float4 h = *(const float4*)(hp + c * 4);
            a0x = fmaf(W[c].x,      h.x, a0x); a0y = fmaf(W[c].y,      h.y, a0y);
            a0z = fmaf(W[c].z,      h.z, a0z); a0w = fmaf(W[c].w,      h.w, a0w);
            a1x = fmaf(W[12 + c].x, h.x, a1x); a1y = fmaf(W[12 + c].y, h.y, a1y);
            a1z = fmaf(W[12 + c].z, h.z, a1z); a1w = fmaf(W[12 + c].w, h.w, a1w);
            a2x = fmaf(W[24 + c].x, h.x, a2x); a2y = fmaf(W[24 + c].y, h.y, a2y);
            a2z = fmaf(W[24 + c].z, h.z, a2z); a2w = fmaf(W[24 + c].w, h.w, a2w);
        }
        float a0 = (a0x + a0y) + (a0z + a0w);
        float a1 = (a1x + a1y) + (a1z + a1w);
        float a2 = (a2x + a2y) + (a2z + a2w);
        a0 += __shfl_xor(a0, 1, 64);
        a1 += __shfl_xor(a1, 1, 64);
        a2 += __shfl_xor(a2, 1, 64);
        float* dp = &dst[i8 * H_SZ + j0];
        if (kh == 0) {
            dp[0] = a0;
            dp[1] = a1;
        } else {
            dp[2] = a2;
        }
    }
}

__global__ __launch_bounds__(384, 2) void rnn3_fused(
    const float* __restrict__ xproj0, // [B*T, 96], includes b_ih0
    const float* __restrict__ w_hh0, const float* __restrict__ b_hh0,
    const float* __restrict__ w_ih1, const float* __restrict__ b_ih1,
    const float* __restrict__ w_hh1, const float* __restrict__ b_hh1,
    const float* __restrict__ w_ih2, const float* __restrict__ b_ih2,
    const float* __restrict__ w_hh2, const float* __restrict__ b_hh2,
    const float* __restrict__ fc_w, const float* __restrict__ fc_b,
    float* __restrict__ out)          // [B]
{
    __shared__ __align__(16) float ring0[RING * H_SZ];   // 12 KB each
    __shared__ __align__(16) float ring1[RING * H_SZ];
    __shared__ __align__(16) float ring2[RING * H_SZ];
    __shared__ __align__(16) float ihd1[2][PP * H_SZ];   // 3 KB each buf
    __shared__ __align__(16) float ihd2[2][PP * H_SZ];
    __shared__ __align__(16) float xpb[2][PP * H_SZ];
    __shared__ float red[H_SZ];

    const int t = threadIdx.x;
    const int b = blockIdx.x;
    const int wv = t >> 6;
    const int l = t & 63;
    const int p = l >> 1, kh = l & 1, j0 = 3 * p;

    // zero rings (h[-1] = 0)
    for (int k = t; k < RING * H_SZ; k += 384) {
        ring0[k] = 0.f; ring1[k] = 0.f; ring2[k] = 0.f;
    }

    const float* xp_base = xproj0 + (size_t)b * T_STEPS * H_SZ;

    // prologue: wave 5 stages xproj chunk 0 (register-staged, v3-proven)
    if (wv == 5) {
#pragma unroll
        for (int q = 0; q < 3; ++q) {
            int idx = (l + 64 * q) * 4;
            *(float4*)&xpb[0][idx] = *(const float4*)&xp_base[idx];
        }
    }
    __syncthreads();

    if (wv < 3) {
        // ---- serial hh recurrence roles ----
        const float* wm = (wv == 0) ? w_hh0 : (wv == 1 ? w_hh1 : w_hh2);
        float4 W[36];
#pragma unroll
        for (int r = 0; r < 3; ++r)
#pragma unroll
            for (int c = 0; c < 12; ++c)
                W[r * 12 + c] = *(const float4*)&wm[(j0 + r) * H_SZ + kh * 48 + c * 4];
        float cb0, cb1, cb2;
        if (wv == 0) {
            cb0 = b_hh0[j0]; cb1 = b_hh0[j0 + 1]; cb2 = b_hh0[j0 + 2];
        } else if (wv == 1) {
            cb0 = b_ih1[j0]     + b_hh1[j0];
            cb1 = b_ih1[j0 + 1] + b_hh1[j0 + 1];
            cb2 = b_ih1[j0 + 2] + b_hh1[j0 + 2];
        } else {
            cb0 = b_ih2[j0]     + b_hh2[j0];
            cb1 = b_ih2[j0 + 1] + b_hh2[j0 + 1];
            cb2 = b_ih2[j0 + 2] + b_hh2[j0 + 2];
        }
        float* ringS = (wv == 0) ? ring0 : (wv == 1 ? ring1 : ring2);
        __builtin_amdgcn_s_setprio(1);   // recurrence is the critical chain
        for (int m = 0; m < NPER; ++m) {
            const int cc = m - 2 * wv;   // w0: m, w1: m-2, w2: m-4
            if (cc >= 0 && cc < NCH) {
                const float* ihsrc = (wv == 0) ? &xpb[m & 1][0]
                                   : (wv == 1) ? &ihd1[cc & 1][0]
                                               : &ihd2[cc & 1][0];
                serial_chunk(W, cb0, cb1, cb2, ringS, ihsrc, cc * PP, p, kh);
            }
            __syncthreads();
        }
        __builtin_amdgcn_s_setprio(0);
    } else if (wv == 3) {
        // ---- ih1 = W_ih1 . h0[t], lag 1 ----
        float4 W[36];
#pragma unroll
        for (int r = 0; r < 3; ++r)
#pragma unroll
            for (int c = 0; c < 12; ++c)
                W[r * 12 + c] = *(const float4*)&w_ih1[(j0 + r) * H_SZ + kh * 48 + c * 4];
        for (int m = 0; m < NPER; ++m) {
            const int cc = m - 1;
            if (cc >= 0 && cc < NCH)
                ih_chunk(W, ring0, &ihd1[cc & 1][0], cc * PP, p, kh);
            __syncthreads();
        }
    } else if (wv == 4) {
        // ---- ih2 = W_ih2 . h1[t], lag 3 ----
        float4 W[36];
#pragma unroll
        for (int r = 0; r < 3; ++r)
#pragma unroll
            for (int c = 0; c < 12; ++c)
                W[r * 12 + c] = *(const float4*)&w_ih2[(j0 + r) * H_SZ + kh * 48 + c * 4];
        for (int m = 0; m < NPER; ++m) {
            const int cc = m - 3;
            if (cc >= 0 && cc < NCH)
                ih_chunk(W, ring1, &ihd2[cc & 1][0], cc * PP, p, kh);
            __syncthreads();
        }
    } else {
        // ---- xproj staging role (register-staged float4, v3-proven) ----
        for (int m = 0; m < NPER; ++m) {
            const int cs = m + 1;
            if (cs < NCH) {
                const float* src = xp_base + (size_t)cs * PP * H_SZ;
                float* dstx = &xpb[cs & 1][0];
#pragma unroll
                for (int q = 0; q < 3; ++q) {
                    int idx = (l + 64 * q) * 4;
                    *(float4*)&dstx[idx] = *(const float4*)&src[idx];
                }
            }
            __syncthreads();
        }
    }

    // h2[T-1] lives in ring2 slot (T-1)&31 = 31 (written before the final
    // barrier of the role loops; barrier counts are uniform across waves)
    if (t < H_SZ) red[t] = ring2[((T_STEPS - 1) & (RING - 1)) * H_SZ + t] * fc_w[t];
    __syncthreads();
    if (t == 0) {
        float sm = 0.f;
#pragma unroll
        for (int k = 0; k < H_SZ; ++k) sm += red[k];
        out[b] = sm + fc_b[0];
    }
}

// ---------------- launcher ----------------
extern "C" void kernel_launch(void* const* d_in, const int* in_sizes, int n_in,
                              void* d_out, int out_size, void* d_ws, size_t ws_size,
                              hipStream_t stream) {
    const float* x     = (const float*)d_in[0];
    const float* w_ih0 = (const float*)d_in[1];
    const float* w_hh0 = (const float*)d_in[2];
    const float* b_ih0 = (const float*)d_in[3];
    const float* b_hh0 = (const float*)d_in[4];
    const float* w_ih1 = (const float*)d_in[5];
    const float* w_hh1 = (const float*)d_in[6];
    const float* b_ih1 = (const float*)d_in[7];
    const float* b_hh1 = (const float*)d_in[8];
    const float* w_ih2 = (const float*)d_in[9];
    const float* w_hh2 = (const float*)d_in[10];
    const float* b_ih2 = (const float*)d_in[11];
    const float* b_hh2 = (const float*)d_in[12];
    const float* fc_w  = (const float*)d_in[13];
    const float* fc_b  = (const float*)d_in[14];

    float* xproj = (float*)d_ws;  // 32768 * 96 floats = 12.6 MB

    const int M = B_SZ * T_STEPS; // 32768
    xproj_gemm<<<M / BM, 256, 0, stream>>>(x, w_ih0, b_ih0, xproj);
    rnn3_fused<<<B_SZ, 384, 0, stream>>>(xproj,
                                         w_hh0, b_hh0,
                                         w_ih1, b_ih1, w_hh1, b_hh1,
                                         w_ih2, b_ih2, w_hh2, b_hh2,
                                         fc_w, fc_b, (float*)d_out);
}